// Round 15
// baseline (98.391 us; speedup 1.0000x reference)
//
#include <hip/hip_runtime.h>

#define B_   64
#define C_   12
#define NC_  16
#define N0_  2048
#define N1_  1000
#define N2_  500
#define N3_  100
#define AGENT __HIP_MEMORY_SCOPE_AGENT
#define NBLK  256
#define TASKS (C_ * (N1_ / 2))   // 6000 phase-A wave-tasks

__device__ __forceinline__ float wred(float v) {
#pragma unroll
    for (int off = 32; off > 0; off >>= 1) v += __shfl_xor(v, off, 64);
    return v;
}

// ===== K0: zero the doneA counter line =====
__global__ void k_zero(int* __restrict__ z) {
    if (threadIdx.x < 16) z[threadIdx.x] = 0;
}

// ===== K_all: phase A (h1) on all 256 blocks; blocks 0..63 continue as round-5 per-b K2. =====
// Handoff = rounds-6/7-proven subset-wait: release (syncthreads+threadfence+ACQ_REL RMW),
// 64 waiters poll RELAXED + s_sleep, acquire via ACQ_REL RMW. All blocks co-resident.
__global__ __launch_bounds__(1024)
void k_all(const float* __restrict__ x, const int* __restrict__ cls,
           const float* __restrict__ W1b, const float* __restrict__ b1b,
           const float* __restrict__ W2b, const float* __restrict__ b2b,
           const float* __restrict__ W3b, const float* __restrict__ b3b,
           const float* __restrict__ W1r, const float* __restrict__ b1r,
           const float* __restrict__ W2r, const float* __restrict__ b2r,
           float* __restrict__ h1, int* __restrict__ doneA,
           float* __restrict__ out_y1, float* __restrict__ out_y2) {
    const int tid  = threadIdx.x;
    const int lane = tid & 63;
    const int wave = tid >> 6;                     // 0..15
    const int cls_lane = cls[lane];

    // ---------------- Phase A: h1 = relu(x·W1b^T + b1b) ----------------
    // Block i owns contiguous task chunk [i*6000/256, (i+1)*6000/256) (23 or 24 tasks):
    // balanced count (+-2%) and ~2 full class cycles per chunk (popularity averaged).
    {
        const int start = (blockIdx.x * TASKS) >> 8;
        const int end   = ((blockIdx.x + 1) * TASKS) >> 8;
        for (int t = start + wave; t < end; t += 16) {
            const int c  = t % C_;
            const int j0 = (t / C_) * 2;           // 0..998
            const unsigned long long m = __ballot(cls_lane == c);
            if (m == 0ull) continue;
            const float4* wr0 = (const float4*)(W1b + ((size_t)c * N1_ + j0) * N0_);
            const float4* wr1 = wr0 + (N0_ / 4);
            float4 w0[8], w1[8];
#pragma unroll
            for (int f = 0; f < 8; ++f) { w0[f] = wr0[f * 64 + lane]; w1[f] = wr1[f * 64 + lane]; }
            const float bias0 = b1b[c * N1_ + j0];
            const float bias1 = b1b[c * N1_ + j0 + 1];
            for (unsigned long long mm = m; mm; mm &= (mm - 1ull)) {
                const int bb = (int)__builtin_ctzll(mm);
                const float4* xr = (const float4*)(x + (size_t)bb * N0_);
                float a0 = 0.f, a1 = 0.f;
#pragma unroll
                for (int f = 0; f < 8; ++f) {
                    const float4 xv = xr[f * 64 + lane];
                    a0 += w0[f].x * xv.x + w0[f].y * xv.y + w0[f].z * xv.z + w0[f].w * xv.w;
                    a1 += w1[f].x * xv.x + w1[f].y * xv.y + w1[f].z * xv.z + w1[f].w * xv.w;
                }
                const float s0 = wred(a0), s1 = wred(a1);
                if (lane == 0) {
                    h1[(size_t)bb * N1_ + j0]     = fmaxf(s0 + bias0, 0.f);
                    h1[(size_t)bb * N1_ + j0 + 1] = fmaxf(s1 + bias1, 0.f);
                }
            }
        }
    }
    __syncthreads();                               // all waves' h1 stores issued
    if (tid == 0) {
        __threadfence();                           // device-scope release
        __hip_atomic_fetch_add(doneA, 1, __ATOMIC_ACQ_REL, AGENT);
    }
    if (blockIdx.x >= B_) return;                  // 192 blocks done; 64 continue

    // ---------------- per-b tail (round-5 K2 verbatim), b = blockIdx.x ----------------
    const int b = blockIdx.x;
    const int c = cls[b];

    __shared__ __align__(16) float s_x[N0_];       // 8 KB
    __shared__ __align__(16) float s_h1[N1_];      // 4 KB
    __shared__ float s_h2[N2_];                    // 2 KB
    __shared__ float s_y1[NC_];
    __shared__ float s_r[N3_];
    __shared__ int   s_e;

    if (tid < 512) ((float4*)s_x)[tid] = ((const float4*)(x + (size_t)b * N0_))[tid];

    if (tid == 0) {                                // subset-wait: 64 spinners
        while (__hip_atomic_load(doneA, __ATOMIC_RELAXED, AGENT) < NBLK)
            __builtin_amdgcn_s_sleep(2);
        __hip_atomic_fetch_add(doneA, 0, __ATOMIC_ACQ_REL, AGENT);   // acquire
    }
    __syncthreads();
    if (tid < 250) ((float4*)s_h1)[tid] = ((const float4*)(h1 + (size_t)b * N1_))[tid];
    __syncthreads();

    // ---- h2[b][j] = relu(h1·W2b[c][j] + b2b), 500 rows, 2/wave/iter ----
    {
        const float4* xr = (const float4*)s_h1;    // 250 float4
        for (int j0 = wave * 2; j0 < N2_; j0 += 32) {
            const float4* wr0 = (const float4*)(W2b + ((size_t)c * N2_ + j0) * N1_);
            const float4* wr1 = wr0 + (N1_ / 4);
            float a0 = 0.f, a1 = 0.f;
#pragma unroll
            for (int f = 0; f < 4; ++f) {
                const int idx = f * 64 + lane;
                if (idx < N1_ / 4) {
                    const float4 xv = xr[idx];
                    const float4 w0 = wr0[idx], w1 = wr1[idx];
                    a0 += w0.x * xv.x + w0.y * xv.y + w0.z * xv.z + w0.w * xv.w;
                    a1 += w1.x * xv.x + w1.y * xv.y + w1.z * xv.z + w1.w * xv.w;
                }
            }
            const float s0 = wred(a0), s1 = wred(a1);
            if (lane == 0) {
                s_h2[j0]     = fmaxf(s0 + b2b[c * N2_ + j0],     0.f);
                s_h2[j0 + 1] = fmaxf(s1 + b2b[c * N2_ + j0 + 1], 0.f);
            }
        }
    }
    __syncthreads();

    // ---- y1[b][m] = h2·W3b[c][m] + b3b, wave m handles m ----
    if (wave < NC_) {
        const float* wrow = W3b + ((size_t)c * NC_ + wave) * N2_;
        float a = 0.f;
        for (int k = lane; k < N2_; k += 64) a += s_h2[k] * wrow[k];
        const float s = wred(a) + b3b[c * NC_ + wave];
        if (lane == 0) { s_y1[wave] = s; out_y1[b * NC_ + wave] = s; }
    }
    __syncthreads();

    // ---- argmax (first occurrence) by wave 0, lanes 0..15 ----
    if (wave == 0) {
        float v  = (lane < NC_) ? s_y1[lane] : -1e30f;
        int   mi = lane;
#pragma unroll
        for (int off = 8; off > 0; off >>= 1) {
            const float ov = __shfl_xor(v,  off, 16);
            const int   om = __shfl_xor(mi, off, 16);
            if (ov > v || (ov == v && om < mi)) { v = ov; mi = om; }
        }
        if (lane == 0) s_e = c * NC_ + mi;
    }
    __syncthreads();
    const int e = s_e;

    // ---- r[b][j] = relu(x·W1r[e][j] + b1r), 100 rows, 2/wave/iter ----
    {
        const float4* xr = (const float4*)s_x;     // 512 float4
        for (int j0 = wave * 2; j0 < N3_; j0 += 32) {
            const float4* wr0 = (const float4*)(W1r + ((size_t)e * N3_ + j0) * N0_);
            const float4* wr1 = wr0 + (N0_ / 4);
            float a0 = 0.f, a1 = 0.f;
#pragma unroll
            for (int f = 0; f < 8; ++f) {
                const int idx = f * 64 + lane;
                const float4 xv = xr[idx];
                const float4 w0 = wr0[idx], w1 = wr1[idx];
                a0 += w0.x * xv.x + w0.y * xv.y + w0.z * xv.z + w0.w * xv.w;
                a1 += w1.x * xv.x + w1.y * xv.y + w1.z * xv.z + w1.w * xv.w;
            }
            const float s0 = wred(a0), s1 = wred(a1);
            if (lane == 0) {
                s_r[j0]     = fmaxf(s0 + b1r[e * N3_ + j0],     0.f);
                s_r[j0 + 1] = fmaxf(s1 + b1r[e * N3_ + j0 + 1], 0.f);
            }
        }
    }
    __syncthreads();

    // ---- y2[b][d] = r·W2r[e][d] + b2r, wave d handles d ----
    if (wave < 3) {
        const float* w2 = W2r + ((size_t)e * 3 + wave) * N3_;
        float a = s_r[lane] * w2[lane];
        if (lane < N3_ - 64) a += s_r[64 + lane] * w2[64 + lane];
        const float s = wred(a);
        if (lane == 0) out_y2[b * 3 + wave] = s + b2r[e * 3 + wave];
    }
}

extern "C" void kernel_launch(void* const* d_in, const int* in_sizes, int n_in,
                              void* d_out, int out_size, void* d_ws, size_t ws_size,
                              hipStream_t stream) {
    const float* x   = (const float*)d_in[0];
    const int*   cls = (const int*)  d_in[1];
    const float* W1b = (const float*)d_in[2];
    const float* b1b = (const float*)d_in[3];
    const float* W2b = (const float*)d_in[4];
    const float* b2b = (const float*)d_in[5];
    const float* W3b = (const float*)d_in[6];
    const float* b3b = (const float*)d_in[7];
    const float* W1r = (const float*)d_in[8];
    const float* b1r = (const float*)d_in[9];
    const float* W2r = (const float*)d_in[10];
    const float* b2r = (const float*)d_in[11];

    float* out_y1 = (float*)d_out;                 // [0, 1024)
    float* out_y2 = (float*)d_out + B_ * NC_;      // [1024, 1216)

    char*  ws    = (char*)d_ws;
    float* h1    = (float*)(ws);                   // 256000 B
    int*   doneA = (int*)  (ws + 256000);          // 64 B line

    hipLaunchKernelGGL(k_zero, dim3(1), dim3(64), 0, stream, doneA);
    hipLaunchKernelGGL(k_all, dim3(NBLK), dim3(1024), 0, stream,
                       x, cls, W1b, b1b, W2b, b2b, W3b, b3b, W1r, b1r, W2r, b2r,
                       h1, doneA, out_y1, out_y2);
}

// Round 16
// 86.223 us; speedup vs baseline: 1.1411x; 1.1411x over previous
//
#include <hip/hip_runtime.h>

#define B_   64
#define C_   12
#define NC_  16
#define N0_  2048
#define N1_  1000
#define N2_  500
#define N3_  100
#define AGENT __HIP_MEMORY_SCOPE_AGENT

__device__ __forceinline__ float wred(float v) {
#pragma unroll
    for (int off = 32; off > 0; off >>= 1) v += __shfl_xor(v, off, 64);
    return v;
}

// ===== K1: h1 = relu(x·W1b^T + b1b). grid (125,12)×256, 2 rows/wave (round-5 proven). =====
// Block (0,0) zeroes the 2064-int control region (doneL2/flag/cnt2).
__global__ __launch_bounds__(256)
void k_l1b(const float* __restrict__ x, const int* __restrict__ cls,
           const float* __restrict__ W1b, const float* __restrict__ b1b,
           float* __restrict__ h1, int* __restrict__ zctrl) {
    if (blockIdx.x == 0 && blockIdx.y == 0) {
        for (int i = threadIdx.x; i < 2064; i += 256) zctrl[i] = 0;
    }
    const int c    = blockIdx.y;
    const int lane = threadIdx.x & 63;
    const int wave = threadIdx.x >> 6;
    const unsigned long long m = __ballot(cls[lane] == c);
    if (m == 0ull) return;

    const int j0 = blockIdx.x * 8 + wave * 2;                 // < 1000 always
    const float4* wr0 = (const float4*)(W1b + ((size_t)c * N1_ + j0) * N0_);
    const float4* wr1 = wr0 + (N0_ / 4);
    float4 w0[8], w1[8];
#pragma unroll
    for (int f = 0; f < 8; ++f) { w0[f] = wr0[f * 64 + lane]; w1[f] = wr1[f * 64 + lane]; }
    const float bias0 = b1b[c * N1_ + j0];
    const float bias1 = b1b[c * N1_ + j0 + 1];

    for (unsigned long long mm = m; mm; mm &= (mm - 1ull)) {
        const int b = (int)__builtin_ctzll(mm);
        const float4* xr = (const float4*)(x + (size_t)b * N0_);
        float a0 = 0.f, a1 = 0.f;
#pragma unroll
        for (int f = 0; f < 8; ++f) {
            const float4 xv = xr[f * 64 + lane];
            a0 += w0[f].x * xv.x + w0[f].y * xv.y + w0[f].z * xv.z + w0[f].w * xv.w;
            a1 += w1[f].x * xv.x + w1[f].y * xv.y + w1[f].z * xv.z + w1[f].w * xv.w;
        }
        const float s0 = wred(a0), s1 = wred(a1);
        if (lane == 0) {
            h1[(size_t)b * N1_ + j0]     = fmaxf(s0 + bias0, 0.f);
            h1[(size_t)b * N1_ + j0 + 1] = fmaxf(s1 + bias1, 0.f);
        }
    }
}

// ===== K2: 256 blocks × 256 thr, three chained roles (all proven patterns). =====
// blk<192:  l2b wave-tasks (round-2 math) -> release doneL2 -> r-helper (b=blk/3, q=blk%3+1)
// blk>=192: tail b=blk-192: spin doneL2 -> y1+argmax -> flag[b] -> r q=0 -> cnt2 finalize y2
// zctrl: doneL2 @0 [16], flag @16 [64*16], cnt2 @1040 [64*16]  (2064 ints)
__global__ __launch_bounds__(256)
void k_tail(const float* __restrict__ x, const int* __restrict__ cls,
            const float* __restrict__ h1, float* __restrict__ h2,
            const float* __restrict__ W2b, const float* __restrict__ b2b,
            const float* __restrict__ W3b, const float* __restrict__ b3b,
            const float* __restrict__ W1r, const float* __restrict__ b1r,
            const float* __restrict__ W2r, const float* __restrict__ b2r,
            int* __restrict__ zctrl, float* __restrict__ y2part,
            float* __restrict__ out_y1, float* __restrict__ out_y2) {
    const int tid  = threadIdx.x;
    const int lane = tid & 63;
    const int wave = tid >> 6;                     // 0..3
    const int blk  = blockIdx.x;

    int* doneL2 = zctrl;                           // [16]
    int* flag   = zctrl + 16;                      // [64*16]
    int* cnt2   = zctrl + 1040;                    // [64*16]

    __shared__ __align__(16) float s_x[N0_];       // 8 KB
    __shared__ float s_h2[N2_];                    // 2 KB
    __shared__ float s_y1[NC_];
    __shared__ float s_part[4][3];
    __shared__ int   s_e;

    int b, q;
    if (blk < 192) {
        // ---------- role 1: class-batched l2b (round-2 k_l2b math) ----------
        const int cls_lane = cls[lane];
        const float4 z4 = make_float4(0.f, 0.f, 0.f, 0.f);
        for (int t = blk * 4 + wave; t < C_ * (N2_ / 2); t += 768) {
            const int c  = t / (N2_ / 2);
            const int j0 = (t % (N2_ / 2)) * 2;
            const unsigned long long m = __ballot(cls_lane == c);
            if (m == 0ull) continue;
            const float4* wr0 = (const float4*)(W2b + ((size_t)c * N2_ + j0) * N1_);
            const float4* wr1 = wr0 + (N1_ / 4);
            float4 w0[4], w1[4];
#pragma unroll
            for (int f = 0; f < 4; ++f) {
                const int idx = f * 64 + lane;
                const bool v = (idx < N1_ / 4);
                w0[f] = v ? wr0[idx] : z4;
                w1[f] = v ? wr1[idx] : z4;
            }
            const float bias0 = b2b[c * N2_ + j0];
            const float bias1 = b2b[c * N2_ + j0 + 1];
            for (unsigned long long mm = m; mm; mm &= (mm - 1ull)) {
                const int bb = (int)__builtin_ctzll(mm);
                const float4* xr = (const float4*)(h1 + (size_t)bb * N1_);
                float a0 = 0.f, a1 = 0.f;
#pragma unroll
                for (int f = 0; f < 4; ++f) {
                    const int idx = f * 64 + lane;
                    const float4 xv = (idx < N1_ / 4) ? xr[idx] : z4;
                    a0 += w0[f].x * xv.x + w0[f].y * xv.y + w0[f].z * xv.z + w0[f].w * xv.w;
                    a1 += w1[f].x * xv.x + w1[f].y * xv.y + w1[f].z * xv.z + w1[f].w * xv.w;
                }
                const float s0 = wred(a0), s1 = wred(a1);
                if (lane == 0) {
                    h2[(size_t)bb * N2_ + j0]     = fmaxf(s0 + bias0, 0.f);
                    h2[(size_t)bb * N2_ + j0 + 1] = fmaxf(s1 + bias1, 0.f);
                }
            }
        }
        __syncthreads();
        if (tid == 0) {                            // release BEFORE any spin (no deadlock)
            __threadfence();
            __hip_atomic_fetch_add(doneL2, 1, __ATOMIC_ACQ_REL, AGENT);
        }
        b = blk / 3;  q = (blk % 3) + 1;
        // stage x[b] for the r-quarter
        for (int i = tid; i < N0_ / 4; i += 256)
            ((float4*)s_x)[i] = ((const float4*)(x + (size_t)b * N0_))[i];
        if (tid == 0) {                            // wait for expert id (round-6/7 pattern)
            int fv;
            while ((fv = __hip_atomic_load(&flag[b * 16], __ATOMIC_RELAXED, AGENT)) == 0)
                __builtin_amdgcn_s_sleep(1);
            s_e = fv - 1;
        }
        __syncthreads();
    } else {
        // ---------- role 2: per-b tail ----------
        b = blk - 192;  q = 0;
        for (int i = tid; i < N0_ / 4; i += 256)
            ((float4*)s_x)[i] = ((const float4*)(x + (size_t)b * N0_))[i];
        if (tid == 0) {                            // subset-wait on l2b completion
            while (__hip_atomic_load(doneL2, __ATOMIC_RELAXED, AGENT) < 192)
                __builtin_amdgcn_s_sleep(2);
            __hip_atomic_fetch_add(doneL2, 0, __ATOMIC_ACQ_REL, AGENT);   // acquire
        }
        __syncthreads();
        for (int i = tid; i < N2_; i += 256) s_h2[i] = h2[(size_t)b * N2_ + i];
        __syncthreads();

        const int c = cls[b];
        for (int mi = wave; mi < NC_; mi += 4) {   // y1: wave handles 4 m's
            const float* wrow = W3b + ((size_t)c * NC_ + mi) * N2_;
            float a = 0.f;
            for (int k = lane; k < N2_; k += 64) a += s_h2[k] * wrow[k];
            const float s = wred(a) + b3b[c * NC_ + mi];
            if (lane == 0) { s_y1[mi] = s; out_y1[b * NC_ + mi] = s; }
        }
        __syncthreads();
        if (wave == 0) {                           // first-occurrence argmax over 16
            float v  = (lane < NC_) ? s_y1[lane] : -1e30f;
            int   mi = lane;
#pragma unroll
            for (int off = 8; off > 0; off >>= 1) {
                const float ov = __shfl_xor(v,  off, 16);
                const int   om = __shfl_xor(mi, off, 16);
                if (ov > v || (ov == v && om < mi)) { v = ov; mi = om; }
            }
            if (lane == 0) s_e = c * NC_ + mi;
        }
        __syncthreads();
        if (tid == 0)
            __hip_atomic_store(&flag[b * 16], 1 + s_e, __ATOMIC_RELEASE, AGENT);
    }

    // ---------- common: r-quarter q for batch b, rows j = 4*idx + q ----------
    const int e = s_e;
    float y2p = 0.f;
    for (int idx = wave; idx < 25; idx += 4) {
        const int j = 4 * idx + q;
        const float4* wr = (const float4*)(W1r + ((size_t)e * N3_ + j) * N0_);
        const float4* xr = (const float4*)s_x;
        float a = 0.f;
#pragma unroll
        for (int f = 0; f < 8; ++f) {
            const int id = f * 64 + lane;
            const float4 wv = wr[id], xv = xr[id];
            a += wv.x * xv.x + wv.y * xv.y + wv.z * xv.z + wv.w * xv.w;
        }
        const float rv = fmaxf(wred(a) + b1r[e * N3_ + j], 0.f);   // all lanes
        if (lane < 3) y2p += rv * W2r[((size_t)e * 3 + lane) * N3_ + j];
    }
    if (lane < 3) s_part[wave][lane] = y2p;
    __syncthreads();
    if (tid < 3) {
        const float t4 = s_part[0][tid] + s_part[1][tid] + s_part[2][tid] + s_part[3][tid];
        y2part[(size_t)(b * 4 + q) * 4 + tid] = t4;                // plain store
    }
    __syncthreads();
    if (tid == 0) {
        __threadfence();
        const int old = __hip_atomic_fetch_add(&cnt2[b * 16], 1, __ATOMIC_ACQ_REL, AGENT);
        if (old == 3) {                            // last of 4 quarters finalizes y2
#pragma unroll
            for (int d = 0; d < 3; ++d) {
                float t5 = b2r[e * 3 + d];
#pragma unroll
                for (int qq = 0; qq < 4; ++qq) t5 += y2part[(size_t)(b * 4 + qq) * 4 + d];
                out_y2[b * 3 + d] = t5;
            }
        }
    }
}

extern "C" void kernel_launch(void* const* d_in, const int* in_sizes, int n_in,
                              void* d_out, int out_size, void* d_ws, size_t ws_size,
                              hipStream_t stream) {
    const float* x   = (const float*)d_in[0];
    const int*   cls = (const int*)  d_in[1];
    const float* W1b = (const float*)d_in[2];
    const float* b1b = (const float*)d_in[3];
    const float* W2b = (const float*)d_in[4];
    const float* b2b = (const float*)d_in[5];
    const float* W3b = (const float*)d_in[6];
    const float* b3b = (const float*)d_in[7];
    const float* W1r = (const float*)d_in[8];
    const float* b1r = (const float*)d_in[9];
    const float* W2r = (const float*)d_in[10];
    const float* b2r = (const float*)d_in[11];

    float* out_y1 = (float*)d_out;                 // [0, 1024)
    float* out_y2 = (float*)d_out + B_ * NC_;      // [1024, 1216)

    char*  ws     = (char*)d_ws;
    float* h1     = (float*)(ws);                  // 256000 B
    float* h2     = (float*)(ws + 256000);         // 128000 B
    int*   zctrl  = (int*)  (ws + 384000);         // 2064 ints = 8256 B (zeroed by K1)
    float* y2part = (float*)(ws + 392256);         // 64*4*4 floats = 4096 B

    hipLaunchKernelGGL(k_l1b, dim3(125, 12), dim3(256), 0, stream,
                       x, cls, W1b, b1b, h1, zctrl);
    hipLaunchKernelGGL(k_tail, dim3(256), dim3(256), 0, stream,
                       x, cls, h1, h2, W2b, b2b, W3b, b3b, W1r, b1r, W2r, b2r,
                       zctrl, y2part, out_y1, out_y2);
}

// Round 17
// 59.584 us; speedup vs baseline: 1.6513x; 1.4471x over previous
//
#include <hip/hip_runtime.h>

#define B_   64
#define C_   12
#define NC_  16
#define N0_  2048
#define N1_  1000
#define N2_  500
#define N3_  100
#define AGENT __HIP_MEMORY_SCOPE_AGENT

__device__ __forceinline__ float wred(float v) {
#pragma unroll
    for (int off = 32; off > 0; off >>= 1) v += __shfl_xor(v, off, 64);
    return v;
}

// ===== K1: h1 = relu(x·W1b^T + b1b). grid (125,12)×256, 2 rows/wave (champion, verbatim). =====
// Block (0,0) zeroes the 2048-int y1acc/cnt region.
__global__ __launch_bounds__(256)
void k_l1b(const float* __restrict__ x, const int* __restrict__ cls,
           const float* __restrict__ W1b, const float* __restrict__ b1b,
           float* __restrict__ h1, int* __restrict__ zctrl) {
    if (blockIdx.x == 0 && blockIdx.y == 0) {
        for (int i = threadIdx.x; i < 2048; i += 256) zctrl[i] = 0;
    }
    const int c    = blockIdx.y;
    const int lane = threadIdx.x & 63;
    const int wave = threadIdx.x >> 6;
    const unsigned long long m = __ballot(cls[lane] == c);
    if (m == 0ull) return;

    const int j0 = blockIdx.x * 8 + wave * 2;                 // < 1000 always
    const float4* wr0 = (const float4*)(W1b + ((size_t)c * N1_ + j0) * N0_);
    const float4* wr1 = wr0 + (N0_ / 4);
    float4 w0[8], w1[8];
#pragma unroll
    for (int f = 0; f < 8; ++f) { w0[f] = wr0[f * 64 + lane]; w1[f] = wr1[f * 64 + lane]; }
    const float bias0 = b1b[c * N1_ + j0];
    const float bias1 = b1b[c * N1_ + j0 + 1];

    for (unsigned long long mm = m; mm; mm &= (mm - 1ull)) {
        const int b = (int)__builtin_ctzll(mm);
        const float4* xr = (const float4*)(x + (size_t)b * N0_);
        float a0 = 0.f, a1 = 0.f;
#pragma unroll
        for (int f = 0; f < 8; ++f) {
            const float4 xv = xr[f * 64 + lane];
            a0 += w0[f].x * xv.x + w0[f].y * xv.y + w0[f].z * xv.z + w0[f].w * xv.w;
            a1 += w1[f].x * xv.x + w1[f].y * xv.y + w1[f].z * xv.z + w1[f].w * xv.w;
        }
        const float s0 = wred(a0), s1 = wred(a1);
        if (lane == 0) {
            h1[(size_t)b * N1_ + j0]     = fmaxf(s0 + bias0, 0.f);
            h1[(size_t)b * N1_ + j0 + 1] = fmaxf(s1 + bias1, 0.f);
        }
    }
}

// ===== K2: 256 blocks × 1024 thr, block (b=blk>>2, q=blk&3). Wait-free last-arrival merge. =====
// Quarter phase: h2 rows j=4*idx+q folded directly into 16 y1-partials (h2 never hits memory).
// Merge: 16 relaxed atomicAdds + 1 ACQ_REL counter. 4th arrival alone runs y1+argmax+r+y2 (R5 code).
__global__ __launch_bounds__(1024)
void k_perb2(const float* __restrict__ x, const int* __restrict__ cls,
             const float* __restrict__ h1,
             const float* __restrict__ W2b, const float* __restrict__ b2b,
             const float* __restrict__ W3b, const float* __restrict__ b3b,
             const float* __restrict__ W1r, const float* __restrict__ b1r,
             const float* __restrict__ W2r, const float* __restrict__ b2r,
             float* __restrict__ y1acc, int* __restrict__ cnt,
             float* __restrict__ out_y1, float* __restrict__ out_y2) {
    const int b    = blockIdx.x >> 2;
    const int q    = blockIdx.x & 3;
    const int tid  = threadIdx.x;
    const int lane = tid & 63;
    const int wave = tid >> 6;                     // 0..15
    const int c    = cls[b];

    __shared__ __align__(16) float s_h1[N1_];      // 4 KB
    __shared__ float s_w3[NC_][125];               // 8 KB (stride 125 odd -> conflict-free)
    __shared__ float s_part[16][NC_];              // 1 KB
    __shared__ __align__(16) float s_x[N0_];       // 8 KB (finalizer only)
    __shared__ float s_r[N3_];
    __shared__ int   s_old;
    __shared__ int   s_e;

    if (tid < 250) ((float4*)s_h1)[tid] = ((const float4*)(h1 + (size_t)b * N1_))[tid];
    for (int i = tid; i < NC_ * 125; i += 1024) {  // W3b[c][mi][4*idx+q]
        const int mi = i / 125, idx = i - mi * 125;
        s_w3[mi][idx] = W3b[((size_t)c * NC_ + mi) * N2_ + 4 * idx + q];
    }
    __syncthreads();

    // ---- quarter phase: rows j = 4*idx+q, y1 partials in lane<16 regs (R7-proven math) ----
    float accm = 0.f;
    for (int idx = wave; idx < 125; idx += 16) {
        const int j = 4 * idx + q;
        const float4* wr = (const float4*)(W2b + ((size_t)c * N2_ + j) * N1_);
        const float4* xr = (const float4*)s_h1;
        float a = 0.f;
#pragma unroll
        for (int f = 0; f < 4; ++f) {
            const int id4 = f * 64 + lane;
            if (id4 < N1_ / 4) {
                const float4 wv = wr[id4], xv = xr[id4];
                a += wv.x * xv.x + wv.y * xv.y + wv.z * xv.z + wv.w * xv.w;
            }
        }
        const float h2v = fmaxf(wred(a) + b2b[c * N2_ + j], 0.f);   // all lanes
        if (lane < NC_) accm += h2v * s_w3[lane][idx];
    }
    if (lane < NC_) s_part[wave][lane] = accm;
    __syncthreads();

    // ---- wait-free merge: 16 relaxed adds + 1 ACQ_REL counter; non-last blocks exit ----
    if (wave == 0 && lane < NC_) {
        float t = 0.f;
#pragma unroll
        for (int w = 0; w < 16; ++w) t += s_part[w][lane];
        __hip_atomic_fetch_add(&y1acc[b * NC_ + lane], t, __ATOMIC_RELAXED, AGENT);
    }
    if (tid == 0) {
        __threadfence();
        s_old = __hip_atomic_fetch_add(&cnt[b * 16], 1, __ATOMIC_ACQ_REL, AGENT);
    }
    __syncthreads();
    if (s_old != 3) return;                        // only the 4th arrival continues

    // ---- finalizer: y1 + argmax (R5 code), then full r-path + y2 (R5 code) ----
    if (tid < 512) ((float4*)s_x)[tid] = ((const float4*)(x + (size_t)b * N0_))[tid];

    if (wave == 0) {
        float v  = -1e30f;
        int   mi = lane;
        if (lane < NC_) {
            v = y1acc[b * NC_ + lane] + b3b[c * NC_ + lane];
            out_y1[b * NC_ + lane] = v;
        }
#pragma unroll
        for (int off = 8; off > 0; off >>= 1) {    // first-occurrence argmax over 16
            const float ov = __shfl_xor(v,  off, 16);
            const int   om = __shfl_xor(mi, off, 16);
            if (ov > v || (ov == v && om < mi)) { v = ov; mi = om; }
        }
        if (lane == 0) s_e = c * NC_ + mi;
    }
    __syncthreads();                               // covers s_x staging + s_e
    const int e = s_e;

    {   // r[b][j] = relu(x·W1r[e][j] + b1r), 100 rows, 2/wave/iter (R5 verbatim)
        const float4* xr = (const float4*)s_x;     // 512 float4
        for (int j0 = wave * 2; j0 < N3_; j0 += 32) {
            const float4* wr0 = (const float4*)(W1r + ((size_t)e * N3_ + j0) * N0_);
            const float4* wr1 = wr0 + (N0_ / 4);
            float a0 = 0.f, a1 = 0.f;
#pragma unroll
            for (int f = 0; f < 8; ++f) {
                const int idx = f * 64 + lane;
                const float4 xv = xr[idx];
                const float4 w0 = wr0[idx], w1 = wr1[idx];
                a0 += w0.x * xv.x + w0.y * xv.y + w0.z * xv.z + w0.w * xv.w;
                a1 += w1.x * xv.x + w1.y * xv.y + w1.z * xv.z + w1.w * xv.w;
            }
            const float s0 = wred(a0), s1 = wred(a1);
            if (lane == 0) {
                s_r[j0]     = fmaxf(s0 + b1r[e * N3_ + j0],     0.f);
                s_r[j0 + 1] = fmaxf(s1 + b1r[e * N3_ + j0 + 1], 0.f);
            }
        }
    }
    __syncthreads();

    if (wave < 3) {                                // y2 (R5 verbatim)
        const float* w2 = W2r + ((size_t)e * 3 + wave) * N3_;
        float a = s_r[lane] * w2[lane];
        if (lane < N3_ - 64) a += s_r[64 + lane] * w2[64 + lane];
        const float s = wred(a);
        if (lane == 0) out_y2[b * 3 + wave] = s + b2r[e * 3 + wave];
    }
}

extern "C" void kernel_launch(void* const* d_in, const int* in_sizes, int n_in,
                              void* d_out, int out_size, void* d_ws, size_t ws_size,
                              hipStream_t stream) {
    const float* x   = (const float*)d_in[0];
    const int*   cls = (const int*)  d_in[1];
    const float* W1b = (const float*)d_in[2];
    const float* b1b = (const float*)d_in[3];
    const float* W2b = (const float*)d_in[4];
    const float* b2b = (const float*)d_in[5];
    const float* W3b = (const float*)d_in[6];
    const float* b3b = (const float*)d_in[7];
    const float* W1r = (const float*)d_in[8];
    const float* b1r = (const float*)d_in[9];
    const float* W2r = (const float*)d_in[10];
    const float* b2r = (const float*)d_in[11];

    float* out_y1 = (float*)d_out;                 // [0, 1024)
    float* out_y2 = (float*)d_out + B_ * NC_;      // [1024, 1216)

    char*  ws    = (char*)d_ws;
    float* h1    = (float*)(ws);                   // 256000 B
    float* y1acc = (float*)(ws + 256000);          // 64*16 floats = 4096 B  (zeroed by K1)
    int*   cnt   = (int*)  (ws + 260096);          // 64*16 ints   = 4096 B  (zeroed by K1)
    int*   zctrl = (int*)  (ws + 256000);          // 2048 ints

    hipLaunchKernelGGL(k_l1b, dim3(125, 12), dim3(256), 0, stream,
                       x, cls, W1b, b1b, h1, zctrl);
    hipLaunchKernelGGL(k_perb2, dim3(256), dim3(1024), 0, stream,
                       x, cls, h1, W2b, b2b, W3b, b3b, W1r, b1r, W2r, b2r,
                       y1acc, cnt, out_y1, out_y2);
}